// Round 4
// baseline (112.448 us; speedup 1.0000x reference)
//
#include <hip/hip_runtime.h>

// NALU B=1024, I=512, O=512 — single fused kernel, fp16 MFMA.
//   w1 = tanh(w_hat)*sigmoid(m_hat)            [I,O]
//   a  = x @ w1 ; s = log(max(|x|,eps)) @ w1 ; m1 = exp(min(s,20))
//   out = g1*a + (1-g1)*m1*clip(ms,-1,1)
// s ~ N(-143, 11^2) here => m1 underflows; ms term guarded exactly: any
// s > -80 takes a cold path computing the true sign-product from wh/mh.
//
// Fusion: each block (tile 32b x 64o, 4 waves, grid 256 = 1 block/CU)
// computes its own w1/x fragments straight into LDS in MFMA fragment order
// (no second dispatch, no global staging). K is split into 2 passes of 256
// so LDS = 64 KB (B 32K + Ax 16K + Al 16K).
// Frag layouts (learn_hip-verified): A[m=lane&15][k=(lane>>4)*8+j],
// B[k=(lane>>4)*8+j][n=lane&15], D[m=(lane>>4)*4+reg][n=lane&15].

#define O_N 512
#define I_N 512

typedef _Float16 f16;
typedef _Float16 f16x8 __attribute__((ext_vector_type(8)));
typedef float f32x4 __attribute__((ext_vector_type(4)));

__device__ __forceinline__ float fast_sigmoid(float v) {
    return 1.0f / (1.0f + __expf(-v));
}
__device__ __forceinline__ float fast_tanh(float v) {
    // exact at the tails: exp(2v)->inf gives 1, ->0 gives -1
    return 1.0f - 2.0f / (1.0f + __expf(2.0f * v));
}

__global__ __launch_bounds__(256) void nalu_fused_kernel(const float* __restrict__ x,
                                                         const float* __restrict__ wh,
                                                         const float* __restrict__ mh,
                                                         const float* __restrict__ g,
                                                         float* __restrict__ out) {
    __shared__ f16x8 lb[4][8][64];    // 32 KB: B frags [n-subtile][k-subtile][lane]
    __shared__ f16x8 lax[2][8][64];   // 16 KB: A frags (x)
    __shared__ f16x8 lal[2][8][64];   // 16 KB: A frags (log|x|)

    const int tid  = threadIdx.x;
    const int lane = tid & 63;
    const int w    = tid >> 6;
    const int wm   = w & 1;           // m-half of block tile
    const int wn   = w >> 1;          // n-half of block tile
    const int o0   = blockIdx.x * 64;
    const int b0   = blockIdx.y * 32;

    f32x4 ca0 = {0.f, 0.f, 0.f, 0.f}, ca1 = ca0, cs0 = ca0, cs1 = ca0;

    for (int kh = 0; kh < 2; ++kh) {
        const int kbase = kh * 256;

        // ---- stage B frags: 2048 frags/pass, 8 per thread, 1 ds_write_b128 each
#pragma unroll
        for (int i = 0; i < 8; ++i) {
            const int f  = tid + 256 * i;
            const int fl = f & 63;
            const int tk = (f >> 6) & 7;
            const int tn = f >> 9;                       // 0..3
            const int n  = o0 + tn * 16 + (fl & 15);
            const int k0 = kbase + tk * 32 + ((fl >> 4) & 3) * 8;
            f16x8 bf;
#pragma unroll
            for (int j = 0; j < 8; ++j) {
                const int idx = (k0 + j) * O_N + n;
                bf[j] = (f16)(fast_tanh(wh[idx]) * fast_sigmoid(mh[idx]));
            }
            lb[tn][tk][fl] = bf;
        }

        // ---- stage A frags: 1024 positions/pass, 4 per thread (x + log|x|)
#pragma unroll
        for (int i = 0; i < 4; ++i) {
            const int f  = tid + 256 * i;
            const int fl = f & 63;
            const int tk = (f >> 6) & 7;
            const int tm = f >> 9;                       // 0..1
            const int m  = b0 + tm * 16 + (fl & 15);
            const int k0 = kbase + tk * 32 + ((fl >> 4) & 3) * 8;
            const float4* x4 = (const float4*)(x + m * I_N + k0);
            const float4 q0 = x4[0], q1 = x4[1];
            const float vx[8] = {q0.x, q0.y, q0.z, q0.w, q1.x, q1.y, q1.z, q1.w};
            f16x8 fx, fv;
#pragma unroll
            for (int j = 0; j < 8; ++j) {
                fx[j] = (f16)vx[j];
                fv[j] = (f16)__logf(fmaxf(fabsf(vx[j]), 1e-7f));
            }
            lax[tm][tk][fl] = fx;
            lal[tm][tk][fl] = fv;
        }

        __syncthreads();

        // ---- MFMA over this K-half
#pragma unroll
        for (int tk = 0; tk < 8; ++tk) {
            const f16x8 ax  = lax[wm][tk][lane];
            const f16x8 al  = lal[wm][tk][lane];
            const f16x8 bf0 = lb[wn * 2][tk][lane];
            const f16x8 bf1 = lb[wn * 2 + 1][tk][lane];
            ca0 = __builtin_amdgcn_mfma_f32_16x16x32_f16(ax, bf0, ca0, 0, 0, 0);
            ca1 = __builtin_amdgcn_mfma_f32_16x16x32_f16(ax, bf1, ca1, 0, 0, 0);
            cs0 = __builtin_amdgcn_mfma_f32_16x16x32_f16(al, bf0, cs0, 0, 0, 0);
            cs1 = __builtin_amdgcn_mfma_f32_16x16x32_f16(al, bf1, cs1, 0, 0, 0);
        }

        __syncthreads();   // safe to overwrite LDS next pass
    }

    // ---- epilogue: D[m=(lane>>4)*4+r][n=lane&15]
    const int col = lane & 15;
    const int rq  = (lane >> 4) * 4;
    const int bb  = b0 + wm * 16 + rq;
#pragma unroll
    for (int t = 0; t < 2; ++t) {
        const int o = o0 + wn * 32 + t * 16 + col;
        const float g1  = fast_sigmoid(g[o]);
        const float omg = 1.0f - g1;
        const f32x4 ca = t ? ca1 : ca0;
        const f32x4 cs = t ? cs1 : cs0;
#pragma unroll
        for (int r = 0; r < 4; ++r) {
            const int b = bb + r;
            const float sv = cs[r];
            const float m1 = __expf(fminf(sv, 20.0f));
            float msv = 1.0f;
            if (sv > -80.0f) {            // cold path (expected never): exact ms
                float p = 1.0f;
                for (int i = 0; i < I_N; ++i) {
                    // ws_oi[o][i] = |w1.flat[o*I+i]| = |w1[row=o][col=i]|
                    const float wv = fabsf(fast_tanh(wh[o * I_N + i]) *
                                           fast_sigmoid(mh[o * I_N + i]));
                    const float xv = x[b * I_N + i];
                    const float sg = (xv > 0.f) ? 1.f : ((xv < 0.f) ? -1.f : 0.f);
                    p *= sg * wv + (1.0f - wv);
                }
                msv = fminf(fmaxf(p, -1.0f), 1.0f);
            }
            out[b * O_N + o] = g1 * ca[r] + omg * m1 * msv;
        }
    }
}

extern "C" void kernel_launch(void* const* d_in, const int* in_sizes, int n_in,
                              void* d_out, int out_size, void* d_ws, size_t ws_size,
                              hipStream_t stream) {
    const float* x  = (const float*)d_in[0];   // [B, I]
    const float* wh = (const float*)d_in[1];   // [I, O]
    const float* mh = (const float*)d_in[2];   // [I, O]
    const float* g  = (const float*)d_in[3];   // [O]
    float* out = (float*)d_out;                // [B, O] fp32

    (void)d_ws; (void)ws_size;                 // no scratch needed anymore

    nalu_fused_kernel<<<dim3(O_N / 64, 1024 / 32), 256, 0, stream>>>(x, wh, mh, g, out);
}

// Round 5
// 68.821 us; speedup vs baseline: 1.6339x; 1.6339x over previous
//
#include <hip/hip_runtime.h>

// NALU B=1024, I=512, O=512 — two dispatches, fp16 MFMA 16x16x32.
//   w1 = tanh(w_hat)*sigmoid(m_hat); a = x@w1; s = log(max(|x|,eps))@w1
//   m1 = exp(min(s,20)); out = g1*a + (1-g1)*m1*clip(ms,-1,1)
// s ~ N(-143,11^2) => m1 underflows to 0; guarded exactly: any s > -80
// takes a cold path computing the true sign-product from wh/mh.
//
// prep: pack A (x, log|x|) and B (w1) as f16 fragments in MFMA order.
//   B-prep is fully coalesced: float4 row reads -> LDS [k][n] tile
//   (b128 writes) -> per-thread fragment gather -> coalesced 16B store.
//   A-prep: fragment k-runs are contiguous in x => direct float4 reads.
// main: grid (16,32)=512 blocks (2 blocks/CU => 2 waves/SIMD, 2x R3's
//   occupancy), block tile 32b x 32o, wave 16b x 16o, B frag shared by
//   the a- and s-GEMMs. No LDS.
// Frag layouts (learn_hip-verified): A[m=lane&15][k=(lane>>4)*8+j],
// B[k=(lane>>4)*8+j][n=lane&15], D[m=(lane>>4)*4+reg][n=lane&15].

#define O_N 512
#define I_N 512
#define B_N 1024

typedef _Float16 f16;
typedef _Float16 f16x8 __attribute__((ext_vector_type(8)));
typedef float f32x4 __attribute__((ext_vector_type(4)));

__device__ __forceinline__ float fast_sigmoid(float v) {
    return 1.0f / (1.0f + __expf(-v));
}
__device__ __forceinline__ float fast_tanh(float v) {
    return 1.0f - 2.0f / (1.0f + __expf(2.0f * v));   // exact at both tails
}

// ---- prep: blocks 0..127 = B frags (32k x 64n tile each), 128..383 = A frags
__global__ __launch_bounds__(256) void prep_kernel(const float* __restrict__ x,
                                                   const float* __restrict__ wh,
                                                   const float* __restrict__ mh,
                                                   f16x8* __restrict__ apx,
                                                   f16x8* __restrict__ apl,
                                                   f16x8* __restrict__ bp) {
    const int tid = threadIdx.x;
    if (blockIdx.x < 128) {
        __shared__ f16 lt[32][72];          // w1 tile [k][n]; 72 = 144B row (16B-mult)
        const int kb = blockIdx.x >> 3;     // 0..15  (k-tile of 32)
        const int nb = blockIdx.x & 7;      // 0..7   (n-tile of 64)
        // read phase: row r (32 rows), 8 consecutive n per thread -> coalesced
        const int r  = tid >> 3;
        const int c0 = (tid & 7) * 8;
        const int base = (kb * 32 + r) * O_N + nb * 64 + c0;
        const float4* w4 = (const float4*)(wh + base);
        const float4* m4 = (const float4*)(mh + base);
        const float4 wa = w4[0], wb = w4[1], ma = m4[0], mb = m4[1];
        f16x8 row;
        row[0] = (f16)(fast_tanh(wa.x) * fast_sigmoid(ma.x));
        row[1] = (f16)(fast_tanh(wa.y) * fast_sigmoid(ma.y));
        row[2] = (f16)(fast_tanh(wa.z) * fast_sigmoid(ma.z));
        row[3] = (f16)(fast_tanh(wa.w) * fast_sigmoid(ma.w));
        row[4] = (f16)(fast_tanh(wb.x) * fast_sigmoid(mb.x));
        row[5] = (f16)(fast_tanh(wb.y) * fast_sigmoid(mb.y));
        row[6] = (f16)(fast_tanh(wb.z) * fast_sigmoid(mb.z));
        row[7] = (f16)(fast_tanh(wb.w) * fast_sigmoid(mb.w));
        *(f16x8*)&lt[r][c0] = row;          // one aligned ds_write_b128
        __syncthreads();
        // frag phase: 256 frags, one per thread
        const int fl  = tid & 63;
        const int tnl = tid >> 6;           // 0..3 local n-subtile
        const int nl  = tnl * 16 + (fl & 15);
        const int k0  = (fl >> 4) * 8;
        f16x8 bf;
#pragma unroll
        for (int j = 0; j < 8; ++j) bf[j] = lt[k0 + j][nl];
        const int tn_g = nb * 4 + tnl;      // global n-tile (0..31)
        bp[tn_g * 1024 + kb * 64 + fl] = bf;
    } else {
        // A frags: x rows are k-contiguous => direct reads, no transpose
        const int t  = (blockIdx.x - 128) * 256 + tid;
        const int fl = t & 63;
        const int tk = (t >> 6) & 15;
        const int tm = t >> 10;             // 0..63
        const int m  = tm * 16 + (fl & 15);
        const int k0 = tk * 32 + (fl >> 4) * 8;
        const float4* x4 = (const float4*)(x + m * I_N + k0);
        const float4 q0 = x4[0], q1 = x4[1];
        const float vx[8] = {q0.x, q0.y, q0.z, q0.w, q1.x, q1.y, q1.z, q1.w};
        f16x8 fx, fv;
#pragma unroll
        for (int j = 0; j < 8; ++j) {
            fx[j] = (f16)vx[j];
            fv[j] = (f16)__logf(fmaxf(fabsf(vx[j]), 1e-7f));
        }
        apx[t] = fx;
        apl[t] = fv;
    }
}

// ---- main: grid (16,32), 256 thr / 4 waves; block 32b x 32o, wave 16b x 16o
__global__ __launch_bounds__(256) void nalu_mfma_kernel(const f16x8* __restrict__ apx,
                                                        const f16x8* __restrict__ apl,
                                                        const f16x8* __restrict__ bp,
                                                        const float* __restrict__ g,
                                                        const float* __restrict__ x,
                                                        const float* __restrict__ wh,
                                                        const float* __restrict__ mh,
                                                        float* __restrict__ out) {
    const int lane = threadIdx.x & 63;
    const int w    = threadIdx.x >> 6;
    const int b0   = blockIdx.y * 32 + (w & 1) * 16;
    const int o0   = blockIdx.x * 32 + (w >> 1) * 16;
    const int tm   = b0 >> 4;
    const int tn   = o0 >> 4;

    f32x4 ca = {0.f, 0.f, 0.f, 0.f}, cs = ca;

    const f16x8* pax = apx + tm * 1024 + lane;
    const f16x8* pal = apl + tm * 1024 + lane;
    const f16x8* pbp = bp  + tn * 1024 + lane;

#pragma unroll 8
    for (int tk = 0; tk < 16; ++tk) {
        const f16x8 ax = pax[tk * 64];
        const f16x8 al = pal[tk * 64];
        const f16x8 bf = pbp[tk * 64];
        ca = __builtin_amdgcn_mfma_f32_16x16x32_f16(ax, bf, ca, 0, 0, 0);
        cs = __builtin_amdgcn_mfma_f32_16x16x32_f16(al, bf, cs, 0, 0, 0);
    }

    // epilogue: D[m=(lane>>4)*4+r][n=lane&15]
    const int col = lane & 15;
    const int rq  = (lane >> 4) * 4;
    const int o   = o0 + col;
    const float g1  = fast_sigmoid(g[o]);
    const float omg = 1.0f - g1;
#pragma unroll
    for (int r = 0; r < 4; ++r) {
        const int b = b0 + rq + r;
        const float sv = cs[r];
        const float m1 = __expf(fminf(sv, 20.0f));
        float msv = 1.0f;
        if (sv > -80.0f) {                  // cold path (expected never): exact ms
            float p = 1.0f;
            for (int i = 0; i < I_N; ++i) {
                // ws_oi[o][i] = |w1.flat[o*I+i]| = |w1[row=o][col=i]|
                const float wv = fabsf(fast_tanh(wh[o * I_N + i]) *
                                       fast_sigmoid(mh[o * I_N + i]));
                const float xv = x[b * I_N + i];
                const float sg = (xv > 0.f) ? 1.f : ((xv < 0.f) ? -1.f : 0.f);
                p *= sg * wv + (1.0f - wv);
            }
            msv = fminf(fmaxf(p, -1.0f), 1.0f);
        }
        out[b * O_N + o] = g1 * ca[r] + omg * m1 * msv;
    }
}

extern "C" void kernel_launch(void* const* d_in, const int* in_sizes, int n_in,
                              void* d_out, int out_size, void* d_ws, size_t ws_size,
                              hipStream_t stream) {
    const float* x  = (const float*)d_in[0];   // [B, I]
    const float* wh = (const float*)d_in[1];   // [I, O]
    const float* mh = (const float*)d_in[2];   // [I, O]
    const float* g  = (const float*)d_in[3];   // [O]
    float* out = (float*)d_out;                // [B, O] fp32

    char* ws = (char*)d_ws;
    f16x8* apx = (f16x8*)ws;                          // 1 MB  (64*16*64 frags)
    f16x8* apl = (f16x8*)(ws + (1u << 20));           // 1 MB
    f16x8* bp  = (f16x8*)(ws + (2u << 20));           // 512 KB (32*16*64 frags)

    prep_kernel<<<384, 256, 0, stream>>>(x, wh, mh, apx, apl, bp);
    nalu_mfma_kernel<<<dim3(16, 32), 256, 0, stream>>>(apx, apl, bp, g, x, wh, mh, out);
}